// Round 2
// baseline (296.335 us; speedup 1.0000x reference)
//
#include <hip/hip_runtime.h>
#include <cstddef>

typedef unsigned short u16;
typedef unsigned int u32;
typedef __attribute__((ext_vector_type(8))) __bf16 bf16x8;
typedef __attribute__((ext_vector_type(4))) float f32x4;

constexpr int kB = 8, kC = 256, kCI = 128, kN = 4096, kM = 1024;
constexpr int kHM = 512;           // m per in-block half
constexpr float kEPS = 1e-5f;
constexpr float kLOG2E = 1.44269504088896f;

__device__ __forceinline__ u16 f2bf(float f) {
    u32 u = __float_as_uint(f);
    u32 r = (u + 0x7fffu + ((u >> 16) & 1u)) >> 16;
    return (u16)r;
}

// ---------------------------------------------------------------------------
// prep: weights -> bf16; fold BN scale into Ww; bb = (bw-mean)*sc+beta
// Wth/bth scaled by log2(e) so softmax runs in exp2 domain.
// ---------------------------------------------------------------------------
__global__ __launch_bounds__(256) void prep_kernel(const float* __restrict__ Wth,
                                                   const float* __restrict__ bth,
                                                   const float* __restrict__ Wph,
                                                   const float* __restrict__ Wg,
                                                   const float* __restrict__ Ww,
                                                   const float* __restrict__ bw,
                                                   const float* __restrict__ gamma,
                                                   const float* __restrict__ beta,
                                                   const float* __restrict__ mean,
                                                   const float* __restrict__ var,
                                                   u16* __restrict__ Wthb,
                                                   u16* __restrict__ Wphb,
                                                   u16* __restrict__ Wgb,
                                                   u16* __restrict__ Wwsb,
                                                   float* __restrict__ bb,
                                                   float* __restrict__ bthl) {
    int idx = blockIdx.x * 256 + threadIdx.x;
    if (idx < 32768) {
        Wthb[idx] = f2bf(Wth[idx] * kLOG2E);
        if (idx < kCI) bthl[idx] = bth[idx] * kLOG2E;
    } else if (idx < 65536) {
        int j = idx - 32768; Wphb[j] = f2bf(Wph[j]);
    } else if (idx < 98304) {
        int j = idx - 65536; Wgb[j] = f2bf(Wg[j]);
    } else {
        int j = idx - 98304;
        int co = j >> 7;
        float sc = gamma[co] * rsqrtf(var[co] + kEPS);
        Wwsb[j] = f2bf(Ww[j] * sc);
        if ((j & 127) == 0) bb[co] = (bw[co] - mean[co]) * sc + beta[co];
    }
}

// ---------------------------------------------------------------------------
// MFMA producer conv1x1 body (optionally fused 2x2 avg-pool on input).
// ---------------------------------------------------------------------------
template <int POOL>
__device__ __forceinline__ void conv_body(const float* __restrict__ x,
                                          const u16* __restrict__ Wb,
                                          const float* __restrict__ bias,
                                          u16* __restrict__ out, int Mn,
                                          int cmajor, int b, int n0) {
    __shared__ __align__(16) u16 w_lds[128 * 72];   // [ci][c] stride 72
    __shared__ __align__(16) u16 x_lds[64 * 64];    // [n][c] swizzled
    int t = threadIdx.x;
    int w = t >> 6, lane = t & 63, l15 = lane & 15, quad = lane >> 4;
    int xn = t & 63, cbb = (t >> 6) * 2;

    f32x4 acc[8];
#pragma unroll
    for (int i = 0; i < 8; i++) acc[i] = (f32x4){0.f, 0.f, 0.f, 0.f};

    for (int c0 = 0; c0 < kC; c0 += 64) {
        __syncthreads();
#pragma unroll
        for (int i = 0; i < 4; i++) {
            int u = t + 256 * i;
            int ci = u >> 3, blk = u & 7;
            *(uint4*)&w_lds[ci * 72 + blk * 8] =
                *(const uint4*)&Wb[ci * kC + c0 + blk * 8];
        }
#pragma unroll
        for (int cc = 0; cc < 2; cc++) {
            int cb = cbb + cc;
            float f[8];
            if (POOL) {
                int p = n0 + xn, ph_ = p >> 5, pw_ = p & 31;
#pragma unroll
                for (int j = 0; j < 8; j++) {
                    const float* src = x + ((size_t)(b * kC + c0 + cb * 8 + j) * 64
                                            + 2 * ph_) * 64 + 2 * pw_;
                    float2 a = *(const float2*)src;
                    float2 b2 = *(const float2*)(src + 64);
                    f[j] = 0.25f * (a.x + a.y + b2.x + b2.y);
                }
            } else {
#pragma unroll
                for (int j = 0; j < 8; j++)
                    f[j] = x[(size_t)(b * kC + c0 + cb * 8 + j) * Mn + n0 + xn];
            }
            uint4 pk;
            pk.x = (u32)f2bf(f[0]) | ((u32)f2bf(f[1]) << 16);
            pk.y = (u32)f2bf(f[2]) | ((u32)f2bf(f[3]) << 16);
            pk.z = (u32)f2bf(f[4]) | ((u32)f2bf(f[5]) << 16);
            pk.w = (u32)f2bf(f[6]) | ((u32)f2bf(f[7]) << 16);
            *(uint4*)&x_lds[xn * 64 + ((cb ^ (xn & 7)) * 8)] = pk;
        }
        __syncthreads();

#pragma unroll
        for (int ks = 0; ks < 2; ks++) {
            int px = w * 16 + l15;
            bf16x8 xf = *(const bf16x8*)&x_lds[px * 64 + (((ks * 4 + quad) ^ (px & 7)) * 8)];
#pragma unroll
            for (int ct = 0; ct < 8; ct++) {
                bf16x8 wf = *(const bf16x8*)&w_lds[(ct * 16 + l15) * 72 + ks * 32 + quad * 8];
                if (cmajor)
                    acc[ct] = __builtin_amdgcn_mfma_f32_16x16x32_bf16(xf, wf, acc[ct], 0, 0, 0);
                else
                    acc[ct] = __builtin_amdgcn_mfma_f32_16x16x32_bf16(wf, xf, acc[ct], 0, 0, 0);
            }
        }
    }

    if (cmajor == 0) {
        int px = n0 + w * 16 + l15;
#pragma unroll
        for (int ct = 0; ct < 8; ct++) {
            int ci0 = ct * 16 + quad * 4;
            uint2 pk;
            pk.x = (u32)f2bf(acc[ct][0] + bias[ci0 + 0]) |
                   ((u32)f2bf(acc[ct][1] + bias[ci0 + 1]) << 16);
            pk.y = (u32)f2bf(acc[ct][2] + bias[ci0 + 2]) |
                   ((u32)f2bf(acc[ct][3] + bias[ci0 + 3]) << 16);
            *(uint2*)&out[(size_t)(b * Mn + px) * kCI + ci0] = pk;
        }
    } else {
        int px = n0 + w * 16 + quad * 4;
#pragma unroll
        for (int ct = 0; ct < 8; ct++) {
            int ci = ct * 16 + l15;
            float bs = bias[ci];
            uint2 pk;
            pk.x = (u32)f2bf(acc[ct][0] + bs) | ((u32)f2bf(acc[ct][1] + bs) << 16);
            pk.y = (u32)f2bf(acc[ct][2] + bs) | ((u32)f2bf(acc[ct][3] + bs) << 16);
            *(uint2*)&out[(size_t)(b * kCI + ci) * Mn + px] = pk;
        }
    }
}

// theta conv: no pool, n-major out (log2e-scaled weights/bias)
__global__ __launch_bounds__(256) void convth_kernel(const float* __restrict__ x,
                                                     const u16* __restrict__ Wb,
                                                     const float* __restrict__ bias,
                                                     u16* __restrict__ out) {
    conv_body<0>(x, Wb, bias, out, kN, 0, blockIdx.y, blockIdx.x * 64);
}

// fused phi (z=0, n-major) + g (z=1, ci-major) convs with pooled input
__global__ __launch_bounds__(256) void convpg_kernel(const float* __restrict__ q,
                                                     const float* __restrict__ v,
                                                     const u16* __restrict__ Wph,
                                                     const u16* __restrict__ Wg,
                                                     const float* __restrict__ bph,
                                                     const float* __restrict__ bg,
                                                     u16* __restrict__ phi,
                                                     u16* __restrict__ g) {
    int z = blockIdx.z;
    conv_body<1>(z ? v : q, z ? Wg : Wph, z ? bg : bph, z ? g : phi,
                 kM, z, blockIdx.y, blockIdx.x * 64);
}

// ---------------------------------------------------------------------------
// Flash attention with IN-BLOCK m-split: 512 thr / 8 waves; waves 0-3 do
// m in [0,512), waves 4-7 do [512,1024), same 64 n rows. Combine via LDS.
// phi staged per half (single buffer, 2 barriers/chunk, reg-prefetched);
// g read DIRECTLY from global ([ci][m] layout -> contiguous 16B A-frags,
// 2MB L2-resident). P via per-wave LDS scatter. exp2-domain, defer-max.
// LDS: phi 2x16KB + P 16KB + ml 0.5KB = 48.5KB -> 2 blocks/CU (16 waves).
// ---------------------------------------------------------------------------
__global__ __launch_bounds__(512, 4) void attn_kernel(const u16* __restrict__ theta,
                                                      const u16* __restrict__ phi,
                                                      const u16* __restrict__ g,
                                                      u16* __restrict__ y) {
    __shared__ __align__(16) u16 ph_lds[2][8192];   // per half [ks:4][m:64][kblk^sw][8]
    __shared__ __align__(16) u16 p_lds[8192];       // [wave:8][frag:2][col:16][k:32]
    __shared__ float mlsh[128];                     // (m,l) per n row from half 1

    int t = threadIdx.x, b = blockIdx.y, n0 = blockIdx.x * 64;
    int w = t >> 6, lane = t & 63, l15 = lane & 15, quad = lane >> 4;
    int half = w >> 2, wl = w & 3, th = t & 255;
    int sw = (l15 >> 1) & 3;

    // theta B-frags in registers (16 n per wave; halves duplicate)
    bf16x8 thf[4];
    const u16* thB = theta + ((size_t)(b * kN) + n0 + wl * 16 + l15) * kCI;
#pragma unroll
    for (int ks = 0; ks < 4; ks++)
        thf[ks] = *(const bf16x8*)&thB[ks * 32 + quad * 8];

    f32x4 oacc[8];
#pragma unroll
    for (int ct = 0; ct < 8; ct++) oacc[ct] = (f32x4){0.f, 0.f, 0.f, 0.f};
    float m_ = -1e30f, l_ = 0.f;

    const u16* phB = phi + ((size_t)b * kM + half * kHM) * kCI;
    const u16* gB  = g + (size_t)b * kCI * kM + half * kHM;
    u16* phh = ph_lds[half];
    u16* pw = p_lds + w * 1024;

    // staging maps (256 threads per half)
    int ldo_[4], go_[4];
#pragma unroll
    for (int i = 0; i < 4; i++) {
        int u = th + 256 * i, row = u >> 4, cb = u & 15;
        ldo_[i] = (cb >> 2) * 2048 + row * 32 + (((cb & 3) ^ ((row >> 1) & 3)) * 8);
        go_[i] = row * kCI + cb * 8;
    }

    uint4 preg[4];
#pragma unroll
    for (int i = 0; i < 4; i++) preg[i] = *(const uint4*)&phB[go_[i]];

    for (int ch = 0; ch < kHM / 64; ++ch) {
        __syncthreads();   // prior chunk's reads of phh done
#pragma unroll
        for (int i = 0; i < 4; i++) *(uint4*)&phh[ldo_[i]] = preg[i];
        __syncthreads();   // writes visible
        if (ch + 1 < kHM / 64) {
            const u16* ns = phB + (ch + 1) * 64 * kCI;
#pragma unroll
            for (int i = 0; i < 4; i++) preg[i] = *(const uint4*)&ns[go_[i]];
        }

        // S' = phi(64m x 128k) . theta^T : C-col = n (log2 domain)
        f32x4 sacc[4];
#pragma unroll
        for (int mt = 0; mt < 4; mt++) sacc[mt] = (f32x4){0.f, 0.f, 0.f, 0.f};
#pragma unroll
        for (int ks = 0; ks < 4; ks++)
#pragma unroll
            for (int mt = 0; mt < 4; mt++) {
                bf16x8 a = *(const bf16x8*)&phh[ks * 2048 + (mt * 16 + l15) * 32 +
                                                ((quad ^ sw) * 8)];
                sacc[mt] = __builtin_amdgcn_mfma_f32_16x16x32_bf16(a, thf[ks], sacc[mt], 0, 0, 0);
            }

        // online softmax (exp2 domain) with defer-max threshold 8
        float mc = -1e30f;
#pragma unroll
        for (int mt = 0; mt < 4; mt++)
#pragma unroll
            for (int r = 0; r < 4; r++) mc = fmaxf(mc, sacc[mt][r]);
        mc = fmaxf(mc, __shfl_xor(mc, 16, 64));
        mc = fmaxf(mc, __shfl_xor(mc, 32, 64));
        if (__any(mc > m_ + 8.0f)) {
            float mn = fmaxf(m_, mc);
            float al = exp2f(m_ - mn);
            m_ = mn;
            l_ *= al;
#pragma unroll
            for (int ct = 0; ct < 8; ct++)
#pragma unroll
                for (int r = 0; r < 4; r++) oacc[ct][r] *= al;
        }
        float rs = 0.f;
#pragma unroll
        for (int mt = 0; mt < 4; mt++)
#pragma unroll
            for (int r = 0; r < 4; r++) {
                float p = exp2f(sacc[mt][r] - m_);
                sacc[mt][r] = p;
                rs += p;
            }
        rs += __shfl_xor(rs, 16, 64);
        rs += __shfl_xor(rs, 32, 64);
        l_ += rs;

        // scatter P' -> per-wave frag LDS (bf16, values <= 2^8)
#pragma unroll
        for (int mt = 0; mt < 4; mt++)
#pragma unroll
            for (int h = 0; h < 2; h++) {
                u32 d = (u32)f2bf(sacc[mt][2 * h]) | ((u32)f2bf(sacc[mt][2 * h + 1]) << 16);
                int m = mt * 16 + quad * 4 + 2 * h;
                int frag = m >> 5;
                int kblk = (m >> 3) & 3;
                int j = (quad & 1) * 4 + 2 * h;
                *(u32*)&pw[frag * 512 + l15 * 32 + ((kblk ^ sw) * 8) + j] = d;
            }

        // O' += G^T(128ci x 64m) . P' — g A-frags straight from global (L2)
        const u16* gC = gB + ch * 64;
#pragma unroll
        for (int ks2 = 0; ks2 < 2; ks2++) {
            bf16x8 bfrag = *(const bf16x8*)&pw[ks2 * 512 + l15 * 32 + ((quad ^ sw) * 8)];
#pragma unroll
            for (int ct = 0; ct < 8; ct++) {
                bf16x8 a = *(const bf16x8*)&gC[(size_t)(ct * 16 + l15) * kM +
                                               ks2 * 32 + quad * 8];
                oacc[ct] = __builtin_amdgcn_mfma_f32_16x16x32_bf16(a, bfrag, oacc[ct], 0, 0, 0);
            }
        }
    }

    // ---- in-block combine: half1 ships (O', m, l) through LDS ----
    __syncthreads();                      // all compute done; LDS reusable
    float* olds = (float*)&ph_lds[0][0];  // [64 n][128 ci] f32, 16B-slot XOR swz
    int nl = wl * 16 + l15;
    if (half == 1) {
#pragma unroll
        for (int ct = 0; ct < 8; ct++) {
            int s = (ct * 4 + quad) ^ (nl & 7);
            *(f32x4*)&olds[nl * 128 + s * 4] = oacc[ct];
        }
        if (quad == 0) { mlsh[2 * nl] = m_; mlsh[2 * nl + 1] = l_; }
    }
    __syncthreads();
    if (half == 0) {
        float m1 = mlsh[2 * nl], l1 = mlsh[2 * nl + 1];
        float mm = fmaxf(m_, m1);
        float w0 = exp2f(m_ - mm), w1 = exp2f(m1 - mm);
        float inv = 1.0f / (l_ * w0 + l1 * w1);
        float a0 = w0 * inv, a1 = w1 * inv;
        u16* yr = y + ((size_t)(b * kN) + n0 + nl) * kCI + quad * 4;
#pragma unroll
        for (int ct = 0; ct < 8; ct++) {
            int s = (ct * 4 + quad) ^ (nl & 7);
            f32x4 o1 = *(const f32x4*)&olds[nl * 128 + s * 4];
            uint2 pk;
            pk.x = (u32)f2bf(oacc[ct][0] * a0 + o1[0] * a1) |
                   ((u32)f2bf(oacc[ct][1] * a0 + o1[1] * a1) << 16);
            pk.y = (u32)f2bf(oacc[ct][2] * a0 + o1[2] * a1) |
                   ((u32)f2bf(oacc[ct][3] * a0 + o1[3] * a1) << 16);
            *(uint2*)&yr[ct * 16] = pk;
        }
    }
}

// ---------------------------------------------------------------------------
// MFMA final conv: out[b][co][n] = Wws(bf16 [256][128]) . y(bf16 [b][n][128])
//                  + bb[co] + v[b][co][n]   (fp32 out)
// ---------------------------------------------------------------------------
__global__ __launch_bounds__(256) void final_kernel(const u16* __restrict__ y,
                                                    const u16* __restrict__ Wws,
                                                    const float* __restrict__ bb,
                                                    const float* __restrict__ v,
                                                    float* __restrict__ out) {
    __shared__ __align__(16) u16 y_lds[64 * 136];
    int t = threadIdx.x, b = blockIdx.y, n0 = blockIdx.x * 64;
    int w = t >> 6, lane = t & 63, l15 = lane & 15, quad = lane >> 4;

#pragma unroll
    for (int i = 0; i < 4; i++) {
        int u = t + 256 * i;
        int row = u >> 4, blk = u & 15;
        *(uint4*)&y_lds[row * 136 + blk * 8] =
            *(const uint4*)&y[(size_t)(b * kN + n0 + row) * kCI + blk * 8];
    }
    __syncthreads();

    bf16x8 af[4];
#pragma unroll
    for (int ks = 0; ks < 4; ks++)
        af[ks] = *(const bf16x8*)&y_lds[(w * 16 + l15) * 136 + ks * 32 + quad * 8];

#pragma unroll
    for (int ct = 0; ct < 16; ct++) {
        f32x4 a = (f32x4){0.f, 0.f, 0.f, 0.f};
#pragma unroll
        for (int ks = 0; ks < 4; ks++) {
            bf16x8 bf = *(const bf16x8*)&Wws[(ct * 16 + l15) * kCI + ks * 32 + quad * 8];
            a = __builtin_amdgcn_mfma_f32_16x16x32_bf16(af[ks], bf, a, 0, 0, 0);
        }
        int co = ct * 16 + l15;
        float bbv = bb[co];
        size_t base = (size_t)(b * kC + co) * kN + n0 + w * 16 + quad * 4;
        float4 vv = *(const float4*)&v[base];
        float4 ov;
        ov.x = a[0] + bbv + vv.x;
        ov.y = a[1] + bbv + vv.y;
        ov.z = a[2] + bbv + vv.z;
        ov.w = a[3] + bbv + vv.w;
        *(float4*)&out[base] = ov;
    }
}

// ---------------------------------------------------------------------------
extern "C" void kernel_launch(void* const* d_in, const int* in_sizes, int n_in,
                              void* d_out, int out_size, void* d_ws, size_t ws_size,
                              hipStream_t stream) {
    (void)in_sizes; (void)n_in; (void)out_size; (void)ws_size;
    const float* q     = (const float*)d_in[0];
    const float* k     = (const float*)d_in[1];
    const float* v     = (const float*)d_in[2];
    const float* Wg    = (const float*)d_in[3];
    const float* bg    = (const float*)d_in[4];
    const float* Wth   = (const float*)d_in[5];
    const float* bth   = (const float*)d_in[6];
    const float* Wph   = (const float*)d_in[7];
    const float* bph   = (const float*)d_in[8];
    const float* Ww    = (const float*)d_in[9];
    const float* bw    = (const float*)d_in[10];
    const float* gamma = (const float*)d_in[11];
    const float* beta  = (const float*)d_in[12];
    const float* mean  = (const float*)d_in[13];
    const float* var   = (const float*)d_in[14];
    float* out = (float*)d_out;

    u16* wsu = (u16*)d_ws;
    u16*   theta = wsu;                       // 4M u16 (8MB)
    u16*   phi   = theta + 4194304;           // 1M u16 (2MB)
    u16*   gbuf  = phi + 1048576;             // 1M u16 (2MB)
    u16*   ybuf  = gbuf + 1048576;            // 4M u16 (8MB)
    u16*   Wthb  = ybuf + 4194304;
    u16*   Wphb  = Wthb + 32768;
    u16*   Wgb   = Wphb + 32768;
    u16*   Wwsb  = Wgb + 32768;
    float* bbuf  = (float*)(Wwsb + 32768);    // 256 f32
    float* bthl  = bbuf + 256;                // 128 f32

    prep_kernel<<<dim3(512), 256, 0, stream>>>(Wth, bth, Wph, Wg, Ww, bw, gamma, beta,
                                               mean, var, Wthb, Wphb, Wgb, Wwsb,
                                               bbuf, bthl);
    convth_kernel<<<dim3(64, 8), 256, 0, stream>>>(k, Wthb, bthl, theta);
    convpg_kernel<<<dim3(16, 8, 2), 256, 0, stream>>>(q, v, Wphb, Wgb, bph, bg, phi, gbuf);
    attn_kernel<<<dim3(64, 8), 512, 0, stream>>>(theta, phi, gbuf, ybuf);
    final_kernel<<<dim3(64, 8), 256, 0, stream>>>(ybuf, Wwsb, bbuf, v, out);
}

// Round 3
// 252.382 us; speedup vs baseline: 1.1742x; 1.1742x over previous
//
#include <hip/hip_runtime.h>
#include <cstddef>

typedef unsigned short u16;
typedef unsigned int u32;
typedef __attribute__((ext_vector_type(8))) __bf16 bf16x8;
typedef __attribute__((ext_vector_type(4))) float f32x4;

constexpr int kB = 8, kC = 256, kCI = 128, kN = 4096, kM = 1024;
constexpr int kHM = 512;           // m per in-block half
constexpr int kCH = 32;            // m per chunk
constexpr int kNCH = kHM / kCH;    // 16 chunks
constexpr float kEPS = 1e-5f;
constexpr float kLOG2E = 1.44269504088896f;

__device__ __forceinline__ u16 f2bf(float f) {
    u32 u = __float_as_uint(f);
    u32 r = (u + 0x7fffu + ((u >> 16) & 1u)) >> 16;
    return (u16)r;
}

__device__ __forceinline__ void gload_lds16(const u16* g, u16* l) {
    __builtin_amdgcn_global_load_lds(
        (const __attribute__((address_space(1))) void*)g,
        (__attribute__((address_space(3))) void*)l, 16, 0, 0);
}

// ---------------------------------------------------------------------------
// prep: weights -> bf16; fold BN scale into Ww; bb = (bw-mean)*sc+beta
// Wth/bth scaled by log2(e) so softmax runs in exp2 domain.
// ---------------------------------------------------------------------------
__global__ __launch_bounds__(256) void prep_kernel(const float* __restrict__ Wth,
                                                   const float* __restrict__ bth,
                                                   const float* __restrict__ Wph,
                                                   const float* __restrict__ Wg,
                                                   const float* __restrict__ Ww,
                                                   const float* __restrict__ bw,
                                                   const float* __restrict__ gamma,
                                                   const float* __restrict__ beta,
                                                   const float* __restrict__ mean,
                                                   const float* __restrict__ var,
                                                   u16* __restrict__ Wthb,
                                                   u16* __restrict__ Wphb,
                                                   u16* __restrict__ Wgb,
                                                   u16* __restrict__ Wwsb,
                                                   float* __restrict__ bb,
                                                   float* __restrict__ bthl) {
    int idx = blockIdx.x * 256 + threadIdx.x;
    if (idx < 32768) {
        Wthb[idx] = f2bf(Wth[idx] * kLOG2E);
        if (idx < kCI) bthl[idx] = bth[idx] * kLOG2E;
    } else if (idx < 65536) {
        int j = idx - 32768; Wphb[j] = f2bf(Wph[j]);
    } else if (idx < 98304) {
        int j = idx - 65536; Wgb[j] = f2bf(Wg[j]);
    } else {
        int j = idx - 98304;
        int co = j >> 7;
        float sc = gamma[co] * rsqrtf(var[co] + kEPS);
        Wwsb[j] = f2bf(Ww[j] * sc);
        if ((j & 127) == 0) bb[co] = (bw[co] - mean[co]) * sc + beta[co];
    }
}

// ---------------------------------------------------------------------------
// MFMA producer conv1x1 body (optionally fused 2x2 avg-pool on input).
// LDS passed in (hoisted to kernel scope so the fused kernel doesn't
// triplicate it).
// ---------------------------------------------------------------------------
template <int POOL>
__device__ __forceinline__ void conv_body(const float* __restrict__ x,
                                          const u16* __restrict__ Wb,
                                          const float* __restrict__ bias,
                                          u16* __restrict__ out, int Mn,
                                          int cmajor, int b, int n0,
                                          u16* w_lds, u16* x_lds) {
    int t = threadIdx.x;
    int w = t >> 6, lane = t & 63, l15 = lane & 15, quad = lane >> 4;
    int xn = t & 63, cbb = (t >> 6) * 2;

    f32x4 acc[8];
#pragma unroll
    for (int i = 0; i < 8; i++) acc[i] = (f32x4){0.f, 0.f, 0.f, 0.f};

    for (int c0 = 0; c0 < kC; c0 += 64) {
        __syncthreads();
#pragma unroll
        for (int i = 0; i < 4; i++) {
            int u = t + 256 * i;
            int ci = u >> 3, blk = u & 7;
            *(uint4*)&w_lds[ci * 72 + blk * 8] =
                *(const uint4*)&Wb[ci * kC + c0 + blk * 8];
        }
#pragma unroll
        for (int cc = 0; cc < 2; cc++) {
            int cb = cbb + cc;
            float f[8];
            if (POOL) {
                int p = n0 + xn, ph_ = p >> 5, pw_ = p & 31;
#pragma unroll
                for (int j = 0; j < 8; j++) {
                    const float* src = x + ((size_t)(b * kC + c0 + cb * 8 + j) * 64
                                            + 2 * ph_) * 64 + 2 * pw_;
                    float2 a = *(const float2*)src;
                    float2 b2 = *(const float2*)(src + 64);
                    f[j] = 0.25f * (a.x + a.y + b2.x + b2.y);
                }
            } else {
#pragma unroll
                for (int j = 0; j < 8; j++)
                    f[j] = x[(size_t)(b * kC + c0 + cb * 8 + j) * Mn + n0 + xn];
            }
            uint4 pk;
            pk.x = (u32)f2bf(f[0]) | ((u32)f2bf(f[1]) << 16);
            pk.y = (u32)f2bf(f[2]) | ((u32)f2bf(f[3]) << 16);
            pk.z = (u32)f2bf(f[4]) | ((u32)f2bf(f[5]) << 16);
            pk.w = (u32)f2bf(f[6]) | ((u32)f2bf(f[7]) << 16);
            *(uint4*)&x_lds[xn * 64 + ((cb ^ (xn & 7)) * 8)] = pk;
        }
        __syncthreads();

#pragma unroll
        for (int ks = 0; ks < 2; ks++) {
            int px = w * 16 + l15;
            bf16x8 xf = *(const bf16x8*)&x_lds[px * 64 + (((ks * 4 + quad) ^ (px & 7)) * 8)];
#pragma unroll
            for (int ct = 0; ct < 8; ct++) {
                bf16x8 wf = *(const bf16x8*)&w_lds[(ct * 16 + l15) * 72 + ks * 32 + quad * 8];
                if (cmajor)
                    acc[ct] = __builtin_amdgcn_mfma_f32_16x16x32_bf16(xf, wf, acc[ct], 0, 0, 0);
                else
                    acc[ct] = __builtin_amdgcn_mfma_f32_16x16x32_bf16(wf, xf, acc[ct], 0, 0, 0);
            }
        }
    }

    if (cmajor == 0) {
        int px = n0 + w * 16 + l15;
#pragma unroll
        for (int ct = 0; ct < 8; ct++) {
            int ci0 = ct * 16 + quad * 4;
            uint2 pk;
            pk.x = (u32)f2bf(acc[ct][0] + bias[ci0 + 0]) |
                   ((u32)f2bf(acc[ct][1] + bias[ci0 + 1]) << 16);
            pk.y = (u32)f2bf(acc[ct][2] + bias[ci0 + 2]) |
                   ((u32)f2bf(acc[ct][3] + bias[ci0 + 3]) << 16);
            *(uint2*)&out[(size_t)(b * Mn + px) * kCI + ci0] = pk;
        }
    } else {
        int px = n0 + w * 16 + quad * 4;
#pragma unroll
        for (int ct = 0; ct < 8; ct++) {
            int ci = ct * 16 + l15;
            float bs = bias[ci];
            uint2 pk;
            pk.x = (u32)f2bf(acc[ct][0] + bs) | ((u32)f2bf(acc[ct][1] + bs) << 16);
            pk.y = (u32)f2bf(acc[ct][2] + bs) | ((u32)f2bf(acc[ct][3] + bs) << 16);
            *(uint2*)&out[(size_t)(b * kCI + ci) * Mn + px] = pk;
        }
    }
}

// ---------------------------------------------------------------------------
// FUSED producers: bx<64 -> theta conv (no pool, n-major, log2e-folded);
// bx in [64,80) -> phi conv (pool, n-major); bx in [80,96) -> g conv
// (pool, ci-major). One launch -> 768 blocks run concurrently (3/CU).
// ---------------------------------------------------------------------------
__global__ __launch_bounds__(256) void convs_kernel(const float* __restrict__ q,
                                                    const float* __restrict__ k,
                                                    const float* __restrict__ v,
                                                    const u16* __restrict__ Wthb,
                                                    const u16* __restrict__ Wphb,
                                                    const u16* __restrict__ Wgb,
                                                    const float* __restrict__ bthl,
                                                    const float* __restrict__ bph,
                                                    const float* __restrict__ bg,
                                                    u16* __restrict__ theta,
                                                    u16* __restrict__ phi,
                                                    u16* __restrict__ g) {
    __shared__ __align__(16) u16 w_lds[128 * 72];
    __shared__ __align__(16) u16 x_lds[64 * 64];
    int bx = blockIdx.x, b = blockIdx.y;
    if (bx < 64) {
        conv_body<0>(k, Wthb, bthl, theta, kN, 0, b, bx * 64, w_lds, x_lds);
    } else {
        int z = (bx >= 80);
        int n0 = (z ? (bx - 80) : (bx - 64)) * 64;
        conv_body<1>(z ? v : q, z ? Wgb : Wphb, z ? bg : bph, z ? g : phi,
                     kM, z, b, n0, w_lds, x_lds);
    }
}

// ---------------------------------------------------------------------------
// Flash attention, in-block m-split: 512 thr / 8 waves; waves 0-3 do
// m in [0,512), waves 4-7 do [512,1024). Combine via LDS at the end.
// phi staged via global_load_lds (async DMA, inverse-swizzled global src,
// linear LDS dest), 32-m chunks, double-buffered, ONE barrier per chunk
// (the barrier's implicit vmcnt drain is the pipeline wait).
// g read directly from global ([ci][m] layout -> contiguous 16B A-frags,
// 2MB L2-resident). P via per-wave LDS. exp2 domain + defer-max(8).
// LDS: phi 2x2x8KB + P 8KB + ml = 40.75KB -> 2 blocks/CU = 16 waves.
// Register budget engineered for launch_bounds(512,4): ~55 VALU-side regs.
// ---------------------------------------------------------------------------
__global__ __launch_bounds__(512, 4) void attn_kernel(const u16* __restrict__ theta,
                                                      const u16* __restrict__ phi,
                                                      const u16* __restrict__ g,
                                                      u16* __restrict__ y) {
    __shared__ __align__(16) u16 ph_lds[2][2][4096]; // [half][buf][ks:4][m:32][slot:4][8]
    __shared__ __align__(16) u16 p_lds[8 * 512];     // per-wave [col:16][k:32]
    __shared__ float mlsh[128];

    int t = threadIdx.x, b = blockIdx.y, n0 = blockIdx.x * 64;
    int w = t >> 6, lane = t & 63, l15 = lane & 15, quad = lane >> 4;
    int half = w >> 2, wl = w & 3, th = t & 255;
    int sw = (l15 >> 1) & 3;

    // theta B-frags in registers (16 n per wave; halves duplicate)
    bf16x8 thf[4];
    const u16* thB = theta + ((size_t)(b * kN) + n0 + wl * 16 + l15) * kCI;
#pragma unroll
    for (int ks = 0; ks < 4; ks++)
        thf[ks] = *(const bf16x8*)&thB[ks * 32 + quad * 8];

    f32x4 oacc[8];
#pragma unroll
    for (int ct = 0; ct < 8; ct++) oacc[ct] = (f32x4){0.f, 0.f, 0.f, 0.f};
    float m_ = -1e30f, l_ = 0.f;

    const u16* phB = phi + ((size_t)b * kM + half * kHM) * kCI;
    const u16* gB  = g + (size_t)b * kCI * kM + half * kHM;
    u16* pw = p_lds + w * 512;

    // inverse-swizzle staging map: linear LDS slot W = th + 256*i (i=0,1),
    // addr16 = W*8; decode ks=W>>7, m=(W>>2)&31, slot=W&3;
    // source cb = (ks<<2) | (slot ^ ((m>>1)&3)); go = m*128 + cb*8.
    int m_st = (th >> 2) & 31;
    int kbx = (th & 3) ^ ((th >> 3) & 3);
    int go0 = m_st * kCI + kbx * 8 + (th >> 7) * 32;   // i=1 adds 64
    u16* dst0 = &ph_lds[half][0][wl * 512];            // i=1 adds 2048

    // prologue: stage chunk 0 into buf 0
    {
        const u16* src = phB + go0;
        gload_lds16(src, dst0);
        gload_lds16(src + 64, dst0 + 2048);
    }

    for (int ch = 0; ch < kNCH; ++ch) {
        asm volatile("s_waitcnt vmcnt(0)" ::: "memory");
        __syncthreads();   // all waves' DMA for chunk ch landed; prev reads done
        if (ch + 1 < kNCH) {
            const u16* src = phB + (ch + 1) * kCH * kCI + go0;
            u16* dst = &ph_lds[half][(ch + 1) & 1][wl * 512];
            gload_lds16(src, dst);
            gload_lds16(src + 64, dst + 2048);
        }
        const u16* buf = &ph_lds[half][ch & 1][0];

        // S' = phi(32m x 128k) . theta^T : 2 mt-tiles, C-col = n (log2 dom)
        f32x4 sacc[2];
#pragma unroll
        for (int mt = 0; mt < 2; mt++) sacc[mt] = (f32x4){0.f, 0.f, 0.f, 0.f};
#pragma unroll
        for (int ks = 0; ks < 4; ks++)
#pragma unroll
            for (int mt = 0; mt < 2; mt++) {
                bf16x8 a = *(const bf16x8*)&buf[ks * 1024 + (mt * 16 + l15) * 32 +
                                                ((quad ^ sw) * 8)];
                sacc[mt] = __builtin_amdgcn_mfma_f32_16x16x32_bf16(a, thf[ks], sacc[mt], 0, 0, 0);
            }

        // online softmax (exp2 domain) with defer-max threshold 8
        float mc = -1e30f;
#pragma unroll
        for (int mt = 0; mt < 2; mt++)
#pragma unroll
            for (int r = 0; r < 4; r++) mc = fmaxf(mc, sacc[mt][r]);
        mc = fmaxf(mc, __shfl_xor(mc, 16, 64));
        mc = fmaxf(mc, __shfl_xor(mc, 32, 64));
        if (__any(mc > m_ + 8.0f)) {
            float mn = fmaxf(m_, mc);
            float al = exp2f(m_ - mn);
            m_ = mn;
            l_ *= al;
#pragma unroll
            for (int ct = 0; ct < 8; ct++)
#pragma unroll
                for (int r = 0; r < 4; r++) oacc[ct][r] *= al;
        }
        float rs = 0.f;
#pragma unroll
        for (int mt = 0; mt < 2; mt++)
#pragma unroll
            for (int r = 0; r < 4; r++) {
                float p = exp2f(sacc[mt][r] - m_);
                sacc[mt][r] = p;
                rs += p;
            }
        rs += __shfl_xor(rs, 16, 64);
        rs += __shfl_xor(rs, 32, 64);
        l_ += rs;

        // scatter P' -> per-wave frag LDS (bf16, values <= 2^8)
#pragma unroll
        for (int mt = 0; mt < 2; mt++)
#pragma unroll
            for (int h = 0; h < 2; h++) {
                u32 d = (u32)f2bf(sacc[mt][2 * h]) | ((u32)f2bf(sacc[mt][2 * h + 1]) << 16);
                int m = mt * 16 + quad * 4 + 2 * h;
                int kblk = (m >> 3) & 3;
                int j = (quad & 1) * 4 + 2 * h;
                *(u32*)&pw[l15 * 32 + ((kblk ^ sw) * 8) + j] = d;
            }

        // O' += G^T(128ci x 32m) . P' — g A-frags straight from global (L2)
        const u16* gC = gB + ch * kCH;
        bf16x8 bfrag = *(const bf16x8*)&pw[l15 * 32 + ((quad ^ sw) * 8)];
#pragma unroll
        for (int ct = 0; ct < 8; ct++) {
            bf16x8 a = *(const bf16x8*)&gC[(size_t)(ct * 16 + l15) * kM + quad * 8];
            oacc[ct] = __builtin_amdgcn_mfma_f32_16x16x32_bf16(a, bfrag, oacc[ct], 0, 0, 0);
        }
    }

    // ---- in-block combine: half1 ships (O', m, l) through LDS ----
    __syncthreads();                         // all compute done; LDS reusable
    float* olds = (float*)&ph_lds[0][0][0];  // [64 n][128 ci] f32 (32KB exact)
    int nl = wl * 16 + l15;
    if (half == 1) {
#pragma unroll
        for (int ct = 0; ct < 8; ct++) {
            int s = (ct * 4 + quad) ^ (nl & 7);
            *(f32x4*)&olds[nl * 128 + s * 4] = oacc[ct];
        }
        if (quad == 0) { mlsh[2 * nl] = m_; mlsh[2 * nl + 1] = l_; }
    }
    __syncthreads();
    if (half == 0) {
        float m1 = mlsh[2 * nl], l1 = mlsh[2 * nl + 1];
        float mm = fmaxf(m_, m1);
        float w0 = exp2f(m_ - mm), w1 = exp2f(m1 - mm);
        float inv = 1.0f / (l_ * w0 + l1 * w1);
        float a0 = w0 * inv, a1 = w1 * inv;
        u16* yr = y + ((size_t)(b * kN) + n0 + nl) * kCI + quad * 4;
#pragma unroll
        for (int ct = 0; ct < 8; ct++) {
            int s = (ct * 4 + quad) ^ (nl & 7);
            f32x4 o1 = *(const f32x4*)&olds[nl * 128 + s * 4];
            uint2 pk;
            pk.x = (u32)f2bf(oacc[ct][0] * a0 + o1[0] * a1) |
                   ((u32)f2bf(oacc[ct][1] * a0 + o1[1] * a1) << 16);
            pk.y = (u32)f2bf(oacc[ct][2] * a0 + o1[2] * a1) |
                   ((u32)f2bf(oacc[ct][3] * a0 + o1[3] * a1) << 16);
            *(uint2*)&yr[ct * 16] = pk;
        }
    }
}

// ---------------------------------------------------------------------------
// MFMA final conv, split over co halves (blockIdx.z):
// out[b][co][n] = Wws . y + bb[co] + v[b][co][n]   (fp32 out)
// ---------------------------------------------------------------------------
__global__ __launch_bounds__(256) void final_kernel(const u16* __restrict__ y,
                                                    const u16* __restrict__ Wws,
                                                    const float* __restrict__ bb,
                                                    const float* __restrict__ v,
                                                    float* __restrict__ out) {
    __shared__ __align__(16) u16 y_lds[64 * 136];
    int t = threadIdx.x, b = blockIdx.y, n0 = blockIdx.x * 64;
    int z = blockIdx.z;
    int w = t >> 6, lane = t & 63, l15 = lane & 15, quad = lane >> 4;

#pragma unroll
    for (int i = 0; i < 4; i++) {
        int u = t + 256 * i;
        int row = u >> 4, blk = u & 15;
        *(uint4*)&y_lds[row * 136 + blk * 8] =
            *(const uint4*)&y[(size_t)(b * kN + n0 + row) * kCI + blk * 8];
    }
    __syncthreads();

    bf16x8 af[4];
#pragma unroll
    for (int ks = 0; ks < 4; ks++)
        af[ks] = *(const bf16x8*)&y_lds[(w * 16 + l15) * 136 + ks * 32 + quad * 8];

#pragma unroll
    for (int ct = 0; ct < 8; ct++) {
        f32x4 a = (f32x4){0.f, 0.f, 0.f, 0.f};
        int co = z * 128 + ct * 16 + l15;
#pragma unroll
        for (int ks = 0; ks < 4; ks++) {
            bf16x8 bf = *(const bf16x8*)&Wws[(size_t)co * kCI + ks * 32 + quad * 8];
            a = __builtin_amdgcn_mfma_f32_16x16x32_bf16(af[ks], bf, a, 0, 0, 0);
        }
        float bbv = bb[co];
        size_t base = (size_t)(b * kC + co) * kN + n0 + w * 16 + quad * 4;
        float4 vv = *(const float4*)&v[base];
        float4 ov;
        ov.x = a[0] + bbv + vv.x;
        ov.y = a[1] + bbv + vv.y;
        ov.z = a[2] + bbv + vv.z;
        ov.w = a[3] + bbv + vv.w;
        *(float4*)&out[base] = ov;
    }
}

// ---------------------------------------------------------------------------
extern "C" void kernel_launch(void* const* d_in, const int* in_sizes, int n_in,
                              void* d_out, int out_size, void* d_ws, size_t ws_size,
                              hipStream_t stream) {
    (void)in_sizes; (void)n_in; (void)out_size; (void)ws_size;
    const float* q     = (const float*)d_in[0];
    const float* k     = (const float*)d_in[1];
    const float* v     = (const float*)d_in[2];
    const float* Wg    = (const float*)d_in[3];
    const float* bg    = (const float*)d_in[4];
    const float* Wth   = (const float*)d_in[5];
    const float* bth   = (const float*)d_in[6];
    const float* Wph   = (const float*)d_in[7];
    const float* bph   = (const float*)d_in[8];
    const float* Ww    = (const float*)d_in[9];
    const float* bw    = (const float*)d_in[10];
    const float* gamma = (const float*)d_in[11];
    const float* beta  = (const float*)d_in[12];
    const float* mean  = (const float*)d_in[13];
    const float* var   = (const float*)d_in[14];
    float* out = (float*)d_out;

    u16* wsu = (u16*)d_ws;
    u16*   theta = wsu;                       // 4M u16 (8MB)
    u16*   phi   = theta + 4194304;           // 1M u16 (2MB)
    u16*   gbuf  = phi + 1048576;             // 1M u16 (2MB)
    u16*   ybuf  = gbuf + 1048576;            // 4M u16 (8MB)
    u16*   Wthb  = ybuf + 4194304;
    u16*   Wphb  = Wthb + 32768;
    u16*   Wgb   = Wphb + 32768;
    u16*   Wwsb  = Wgb + 32768;
    float* bbuf  = (float*)(Wwsb + 32768);    // 256 f32
    float* bthl  = bbuf + 256;                // 128 f32

    prep_kernel<<<dim3(512), 256, 0, stream>>>(Wth, bth, Wph, Wg, Ww, bw, gamma, beta,
                                               mean, var, Wthb, Wphb, Wgb, Wwsb,
                                               bbuf, bthl);
    convs_kernel<<<dim3(96, 8), 256, 0, stream>>>(q, k, v, Wthb, Wphb, Wgb,
                                                  bthl, bph, bg, theta, phi, gbuf);
    attn_kernel<<<dim3(64, 8), 512, 0, stream>>>(theta, phi, gbuf, ybuf);
    final_kernel<<<dim3(64, 8, 2), 256, 0, stream>>>(ybuf, Wwsb, bbuf, v, out);
}